// Round 12
// baseline (81.062 us; speedup 1.0000x reference)
//
#include <hip/hip_runtime.h>

// out[1024][1024] = relu(a @ feats^T) @ relu(b @ feats^T)^T
//   a,b: [1024][2048] fp32, feats: [128][2048] fp32, out fp32.
// Pipeline (2 dispatches):
//   gemm1_onebar_red: grid (32,8) = 64-row M-stripes x 8 K-splits, R11's
//     single-barrier body. Partials are stored via RELAXED AGENT-scope
//     atomics (LLC-routed, bypassing the non-coherent per-XCD L2s - no
//     threadfence / wbL2, which was R6's +77 us). Per-stripe counter in
//     __device__ bss; the LAST arriver (no spin) re-reads all 8 partials
//     for its stripe via LLC loads (coalesced, ~256 KB), relu+cvt, writes
//     bf16 fk[2048][128]. Ordering: pre-barrier vmcnt(0) drains stores;
//     winner's loads are ordered by the data-dependent branch on the RMW.
//   gemm2: 64x64 out tiles via MFMA on relu'd bf16 fk (R4-verbatim).
// Measured lessons: grid.sync (R1), per-elem data atomics (R2), consumer-
// fused reduce (R5: 16x amp), __threadfence+ctr (R6: serialized L2 wb),
// full-K-per-block (R3/R7/R8), TLP-x2 (R10) all lose. Staging fully
// coalesced (R8/R9). ~43 us ws poison-fill is a fixed term in the window.

typedef __attribute__((ext_vector_type(8))) __bf16 bf16x8;
typedef __attribute__((ext_vector_type(4))) __bf16 bf16x4;
typedef __attribute__((ext_vector_type(4))) float floatx4;
typedef unsigned long long u64;

#define KD     2048   // inner K of gemm1
#define NF     128    // feature count = K of gemm2
#define NA     1024   // rows of a (= rows of b = out dim)
#define NPART  8      // K-splits (K=256 each)
#define KSL    256    // K per split
#define FKN    (2048 * 128)

#define XSZ    (64 * 72)    // bf16 elems per X chunk buffer
#define FSZ    (128 * 72)   // bf16 elems per F chunk buffer

__device__ int g_ctr[32];   // per-stripe completion counters (bss=0, self-cleaning)

static __device__ inline bf16x4 cvt4(float4 u) {
    bf16x4 s;
    s[0] = (__bf16)u.x; s[1] = (__bf16)u.y; s[2] = (__bf16)u.z; s[3] = (__bf16)u.w;
    return s;
}

// LLC-routed accessors: RELAXED AGENT atomics bypass the XCD L2s (which may
// hold stale poison from the per-iteration ws fill) with no cache-maintenance.
static __device__ inline void llc_store(float* p, float v) {
    __hip_atomic_store(p, v, __ATOMIC_RELAXED, __HIP_MEMORY_SCOPE_AGENT);
}
static __device__ inline float4 llc_load4(const float* p) {
    u64 lo = __hip_atomic_load((const u64*)p,     __ATOMIC_RELAXED, __HIP_MEMORY_SCOPE_AGENT);
    u64 hi = __hip_atomic_load((const u64*)p + 1, __ATOMIC_RELAXED, __HIP_MEMORY_SCOPE_AGENT);
    float4 v;
    v.x = __uint_as_float((unsigned)(lo & 0xffffffffu));
    v.y = __uint_as_float((unsigned)(lo >> 32));
    v.z = __uint_as_float((unsigned)(hi & 0xffffffffu));
    v.w = __uint_as_float((unsigned)(hi >> 32));
    return v;
}

struct Chunk {
    float4 x[4];   // X rows srow+16j, j=0..3
    float4 f[8];   // F rows srow+16i, i=0..7
};

static __device__ inline void load_chunk(Chunk& ch, const float* xp,
                                         const float* fp, int koff) {
#pragma unroll
    for (int j = 0; j < 4; j++)
        ch.x[j] = *(const float4*)(xp + (size_t)j * 16 * KD + koff);
#pragma unroll
    for (int i = 0; i < 8; i++)
        ch.f[i] = *(const float4*)(fp + (size_t)i * 16 * KD + koff);
}

static __device__ inline void write_chunk(const Chunk& ch, __bf16* Xc, __bf16* Fc,
                                          int srow, int scol) {
#pragma unroll
    for (int j = 0; j < 4; j++)
        *(bf16x4*)&Xc[(srow + 16 * j) * 72 + scol] = cvt4(ch.x[j]);
#pragma unroll
    for (int i = 0; i < 8; i++)
        *(bf16x4*)&Fc[(srow + 16 * i) * 72 + scol] = cvt4(ch.f[i]);
}

// ---- gemm1_onebar_red: partials (LLC) + last-arriver stripe reduce ----
__global__ __launch_bounds__(256) void gemm1_onebar_red(const float* __restrict__ A,
                                                        const float* __restrict__ B,
                                                        const float* __restrict__ F,
                                                        float* __restrict__ part,
                                                        __bf16* __restrict__ fkb) {
    __shared__ __attribute__((aligned(16))) __bf16 smem[4 * XSZ + 4 * FSZ]; // 108 KB
    __shared__ int s_old;
    __bf16* Xs = smem;              // 4 chunks of [64][72]
    __bf16* Fs = smem + 4 * XSZ;    // 4 chunks of [128][72]

    const int t    = threadIdx.x;
    const int m0   = blockIdx.x * 64;
    const int s    = blockIdx.y;
    const int k0   = s * KSL;
    const float* src = (m0 < NA) ? (A + (size_t)m0 * KD)
                                 : (B + (size_t)(m0 - NA) * KD);

    const int lane = t & 63;
    const int w    = t >> 6;
    const int ln   = lane & 15;
    const int quad = lane >> 4;
    const int q8   = quad * 8;

    // coalesced staging coordinates (shared by X and F)
    const int srow = t >> 4;          // 0..15
    const int scol = (t & 15) * 4;    // float col 0..60 within a 64-col chunk
    const float* xp = src + (size_t)srow * KD + (k0 + scol);  // X rows srow+16j
    const float* fp = F   + (size_t)srow * KD + (k0 + scol);  // F rows srow+16i

    // 2-deep ping-pong: chunk c+1's loads in flight while c writes to LDS
    Chunk ca, cb;
    load_chunk(ca, xp, fp, 0);
    load_chunk(cb, xp, fp, 64);
    write_chunk(ca, Xs + 0 * XSZ, Fs + 0 * FSZ, srow, scol);
    load_chunk(ca, xp, fp, 128);
    write_chunk(cb, Xs + 1 * XSZ, Fs + 1 * FSZ, srow, scol);
    load_chunk(cb, xp, fp, 192);
    write_chunk(ca, Xs + 2 * XSZ, Fs + 2 * FSZ, srow, scol);
    write_chunk(cb, Xs + 3 * XSZ, Fs + 3 * FSZ, srow, scol);
    __syncthreads();   // the only barrier of the main body

    floatx4 acc[4][2];
#pragma unroll
    for (int mt = 0; mt < 4; mt++)
#pragma unroll
        for (int nt = 0; nt < 2; nt++)
            acc[mt][nt] = (floatx4){0.f, 0.f, 0.f, 0.f};

#pragma unroll
    for (int c = 0; c < 4; c++) {
        const __bf16* Xc = Xs + c * XSZ;
        const __bf16* Fc = Fs + c * FSZ;
#pragma unroll
        for (int sub = 0; sub < 64; sub += 32) {
            bf16x8 bfrag[2];
#pragma unroll
            for (int nt = 0; nt < 2; nt++)
                bfrag[nt] = *(const bf16x8*)&Fc[(w * 32 + nt * 16 + ln) * 72 + sub + q8];
#pragma unroll
            for (int mt = 0; mt < 4; mt++) {
                bf16x8 af = *(const bf16x8*)&Xc[(mt * 16 + ln) * 72 + sub + q8];
#pragma unroll
                for (int nt = 0; nt < 2; nt++)
                    acc[mt][nt] = __builtin_amdgcn_mfma_f32_16x16x32_bf16(
                        af, bfrag[nt], acc[mt][nt], 0, 0, 0);
            }
        }
    }

    // store this split's partial, LLC-routed (bypasses non-coherent L2s)
    float* pdst = part + (size_t)s * FKN;
#pragma unroll
    for (int mt = 0; mt < 4; mt++)
#pragma unroll
        for (int nt = 0; nt < 2; nt++)
#pragma unroll
            for (int r = 0; r < 4; r++) {
                int row = m0 + mt * 16 + quad * 4 + r;
                int col = w * 32 + nt * 16 + ln;
                llc_store(&pdst[(size_t)row * NF + col], acc[mt][nt][r]);
            }

    // completion count. The barrier's implicit vmcnt(0) drains every wave's
    // LLC stores before any thread can pass; t==0 then bumps the counter.
    __syncthreads();
    if (t == 0)
        s_old = __hip_atomic_fetch_add(&g_ctr[blockIdx.x], 1,
                                       __ATOMIC_RELAXED, __HIP_MEMORY_SCOPE_AGENT);
    __syncthreads();

    if (s_old == NPART - 1) {   // last arriver: all 8 partials are in LLC
        asm volatile("" ::: "memory");   // compiler fence; HW ordered by branch dep
#pragma unroll
        for (int jj = 0; jj < 8; jj++) {
            const int g    = jj * 256 + t;       // 2048 float4 jobs in stripe
            const int row  = g >> 5;             // 0..63
            const int col4 = (g & 31) * 4;       // 0..124
            const float* p = part + (size_t)(m0 + row) * NF + col4;
            float4 sum = make_float4(0.f, 0.f, 0.f, 0.f);
#pragma unroll
            for (int s2 = 0; s2 < NPART; s2++) {
                float4 u = llc_load4(p + (size_t)s2 * FKN);
                sum.x += u.x; sum.y += u.y; sum.z += u.z; sum.w += u.w;
            }
            bf16x4 o;
            o[0] = (__bf16)fmaxf(sum.x, 0.f);
            o[1] = (__bf16)fmaxf(sum.y, 0.f);
            o[2] = (__bf16)fmaxf(sum.z, 0.f);
            o[3] = (__bf16)fmaxf(sum.w, 0.f);
            *(bf16x4*)(fkb + (size_t)(m0 + row) * NF + col4) = o;
        }
        if (t == 0)   // self-clean for the next graph replay
            __hip_atomic_store(&g_ctr[blockIdx.x], 0,
                               __ATOMIC_RELAXED, __HIP_MEMORY_SCOPE_AGENT);
    }
}

// ---- gemm2: out[i][j] = sum_f fkb[i][f] * fkb[1024+j][f] (already relu'd) ----
// grid (16,16): 64x64 out tiles; block = 4 waves in 2x2. (R4-verbatim)
__global__ __launch_bounds__(256) void gemm2(const __bf16* __restrict__ fkb,
                                             float* __restrict__ out) {
    __shared__ __bf16 Ps[64 * 136];
    __shared__ __bf16 Qs[64 * 136];

    const int t    = threadIdx.x;
    const int i0   = blockIdx.y * 64;
    const int j0   = blockIdx.x * 64;
    const int lane = t & 63;
    const int w    = t >> 6;
    const int wm   = w & 1;
    const int wn   = w >> 1;
    const int ln   = lane & 15;
    const int quad = lane >> 4;
    const int q8   = quad * 8;

    const int prow = t >> 2, pcol = (t & 3) * 32;
    {
        const __bf16* p = fkb + (size_t)(i0 + prow) * NF + pcol;
        const __bf16* q = fkb + (size_t)(NA + j0 + prow) * NF + pcol;
#pragma unroll
        for (int c = 0; c < 32; c += 8) {
            *(bf16x8*)&Ps[prow * 136 + pcol + c] = *(const bf16x8*)(p + c);
            *(bf16x8*)&Qs[prow * 136 + pcol + c] = *(const bf16x8*)(q + c);
        }
    }
    __syncthreads();

    floatx4 acc[2][2];
#pragma unroll
    for (int mt = 0; mt < 2; mt++)
#pragma unroll
        for (int nt = 0; nt < 2; nt++)
            acc[mt][nt] = (floatx4){0.f, 0.f, 0.f, 0.f};

#pragma unroll
    for (int k0 = 0; k0 < 128; k0 += 32) {
        bf16x8 af[2], bf[2];
#pragma unroll
        for (int mt = 0; mt < 2; mt++)
            af[mt] = *(const bf16x8*)&Ps[(wm * 32 + mt * 16 + ln) * 136 + k0 + q8];
#pragma unroll
        for (int nt = 0; nt < 2; nt++)
            bf[nt] = *(const bf16x8*)&Qs[(wn * 32 + nt * 16 + ln) * 136 + k0 + q8];
#pragma unroll
        for (int mt = 0; mt < 2; mt++)
#pragma unroll
            for (int nt = 0; nt < 2; nt++)
                acc[mt][nt] = __builtin_amdgcn_mfma_f32_16x16x32_bf16(
                    af[mt], bf[nt], acc[mt][nt], 0, 0, 0);
    }

#pragma unroll
    for (int mt = 0; mt < 2; mt++)
#pragma unroll
        for (int nt = 0; nt < 2; nt++)
#pragma unroll
            for (int r = 0; r < 4; r++) {
                int row = i0 + wm * 32 + mt * 16 + quad * 4 + r;
                int col = j0 + wn * 32 + nt * 16 + ln;
                out[(size_t)row * 1024 + col] = acc[mt][nt][r];
            }
}

extern "C" void kernel_launch(void* const* d_in, const int* in_sizes, int n_in,
                              void* d_out, int out_size, void* d_ws, size_t ws_size,
                              hipStream_t stream) {
    const float* a     = (const float*)d_in[0];
    const float* b     = (const float*)d_in[1];
    const float* feats = (const float*)d_in[2];
    float* out = (float*)d_out;

    float*   part = (float*)d_ws;                                      // 8 MB fp32 partials
    __bf16*  fkb  = (__bf16*)((char*)d_ws + (size_t)NPART * FKN * 4);  // 512 KB bf16

    gemm1_onebar_red<<<dim3(32, NPART), 256, 0, stream>>>(a, b, feats, part, fkb);
    gemm2<<<dim3(16, 16), 256, 0, stream>>>(fkb, out);
}